// Round 1
// baseline (81.788 us; speedup 1.0000x reference)
//
#include <hip/hip_runtime.h>

// AFMAttentionLayer: s[b,i,j] = sum_d x[b,i,d]*x[b,j,d]*wsum[d] + bsum,
// out = s / denom[b], denom[b] = sum_d S_d^2*wsum[d] + F*F*bsum, S_d = sum_i x[b,i,d].
// B=4096, F=64, D=128, H=4.

constexpr int F = 64;
constexpr int D = 128;
constexpr int LDT = 68;   // padded row stride (floats) for transposed x tile: 68%32=4 -> conflict-free float4 reads

__global__ __launch_bounds__(256, 4) void afm_kernel(
    const float* __restrict__ x, const float* __restrict__ w,
    const float* __restrict__ bias, float* __restrict__ out)
{
    __shared__ float sXt[D * LDT];   // x^T for this batch: sXt[d][i]
    __shared__ float sW[D];          // wsum[d] = sum_h w[h,d]
    __shared__ float sDen;

    const int t   = threadIdx.x;
    const int blk = blockIdx.x;

    if (t < D) sW[t] = w[t] + w[D + t] + w[2 * D + t] + w[3 * D + t];
    if (t == 0) sDen = 0.0f;
    const float bsum = bias[0] + bias[1] + bias[2] + bias[3];

    // ---- stage x[blk] transposed into LDS (coalesced global float4 reads) ----
    const float* xb = x + (size_t)blk * (F * D);
    #pragma unroll
    for (int k = 0; k < 8; ++k) {
        const int f   = k * 1024 + t * 4;          // flat float index in [0, 8192)
        const float4 v = *reinterpret_cast<const float4*>(xb + f);
        const int row = f >> 7;                    // i
        const int col = f & 127;                   // d
        sXt[(col + 0) * LDT + row] = v.x;
        sXt[(col + 1) * LDT + row] = v.y;
        sXt[(col + 2) * LDT + row] = v.z;
        sXt[(col + 3) * LDT + row] = v.w;
    }
    __syncthreads();

    // ---- denominator: closed form ----
    if (t < D) {
        float S = 0.0f;
        #pragma unroll
        for (int i = 0; i < F; i += 4) {
            const float4 v = *reinterpret_cast<const float4*>(&sXt[t * LDT + i]);
            S += (v.x + v.y) + (v.z + v.w);
        }
        float p = S * S * sW[t];
        #pragma unroll
        for (int off = 32; off > 0; off >>= 1) p += __shfl_down(p, off, 64);
        if ((t & 63) == 0) atomicAdd(&sDen, p);
    }
    __syncthreads();

    const float denom = sDen + (float)(F * F) * bsum;
    const float rden  = 1.0f / denom;

    // ---- each thread computes a 4x4 output tile ----
    const int i0 = (t >> 4) << 2;   // output row base
    const int j0 = (t & 15) << 2;   // output col base

    float acc[4][4] = {{0.f, 0.f, 0.f, 0.f},
                       {0.f, 0.f, 0.f, 0.f},
                       {0.f, 0.f, 0.f, 0.f},
                       {0.f, 0.f, 0.f, 0.f}};

    #pragma unroll 4
    for (int d = 0; d < D; ++d) {
        const float ws  = sW[d];
        const float4 xi = *reinterpret_cast<const float4*>(&sXt[d * LDT + i0]);
        const float4 xj = *reinterpret_cast<const float4*>(&sXt[d * LDT + j0]);
        const float xiw[4] = {xi.x * ws, xi.y * ws, xi.z * ws, xi.w * ws};
        const float xjv[4] = {xj.x, xj.y, xj.z, xj.w};
        #pragma unroll
        for (int a = 0; a < 4; ++a)
            #pragma unroll
            for (int q = 0; q < 4; ++q)
                acc[a][q] = fmaf(xiw[a], xjv[q], acc[a][q]);
    }

    // ---- epilogue: add bsum, scale by 1/denom, coalesced float4 stores ----
    const size_t obase = (size_t)blk * (F * F);
    #pragma unroll
    for (int a = 0; a < 4; ++a) {
        float4 o;
        o.x = (acc[a][0] + bsum) * rden;
        o.y = (acc[a][1] + bsum) * rden;
        o.z = (acc[a][2] + bsum) * rden;
        o.w = (acc[a][3] + bsum) * rden;
        *reinterpret_cast<float4*>(&out[obase + (size_t)(i0 + a) * F + j0]) = o;
    }
}

extern "C" void kernel_launch(void* const* d_in, const int* in_sizes, int n_in,
                              void* d_out, int out_size, void* d_ws, size_t ws_size,
                              hipStream_t stream) {
    const float* x  = (const float*)d_in[0];   // [4096, 64, 128]
    const float* w  = (const float*)d_in[1];   // [4, 128]
    const float* b  = (const float*)d_in[2];   // [4]
    float* out      = (float*)d_out;           // [4096, 64, 64]

    afm_kernel<<<4096, 256, 0, stream>>>(x, w, b, out);
}

// Round 2
// 45.398 us; speedup vs baseline: 1.8016x; 1.8016x over previous
//
#include <hip/hip_runtime.h>
#include <hip/hip_bf16.h>

// AFMAttentionLayer: s[b,i,j] = sum_d x[b,i,d]*x[b,j,d]*wsum[d] + bsum
// out = s / denom[b];  denom[b] = sum_d S_d^2*wsum[d] + F*F*bsum  (fp32 closed form,
// kept in fp32 because the reference denominator has heavy cancellation).
// Numerator Gram matrix via bf16 MFMA: A = bf16(X*diag(wsum)), B = bf16(X), s = A*B^T.
// B=4096, F=64, D=128, H=4.

constexpr int F = 64;
constexpr int D = 128;

using bf16x8 = __attribute__((ext_vector_type(8))) short;  // 8 bf16 = 4 VGPRs
using f32x4  = __attribute__((ext_vector_type(4))) float;

// Chunked+swizzled LDS tile: chunk = d>>3 (16), row (64), e = d&7.
// byte addr = ((((chunk<<6)+row)<<4) ^ ((chunk&7)<<4)) + 2*e
// -> bank slot = (row&7)^(chunk&7): balanced for both staging writes (row const,
//    chunk varies) and MFMA fragment reads (rows vary, chunk const).
__device__ __forceinline__ int tile_addr(int chunk, int row) {
    return ((((chunk << 6) + row) << 4) ^ ((chunk & 7) << 4));
}

__device__ __forceinline__ unsigned bf_rne(float f) {
    unsigned u = __float_as_uint(f);
    return (u + 0x7FFFu + ((u >> 16) & 1u)) >> 16;
}
__device__ __forceinline__ unsigned pack2(float lo, float hi) {
    return bf_rne(lo) | (bf_rne(hi) << 16);
}

__global__ __launch_bounds__(256, 4) void afm_kernel(
    const float* __restrict__ x, const float* __restrict__ w,
    const float* __restrict__ bias, float* __restrict__ out)
{
    __shared__ short sA[F * D];   // bf16 X*wsum tile
    __shared__ short sB[F * D];   // bf16 X tile
    __shared__ float sW[D];
    __shared__ float sS[D];
    __shared__ float sDen;

    const int t    = threadIdx.x;
    const int blk  = blockIdx.x;
    const int lane = t & 63;
    const int wv   = t >> 6;          // wave id 0..3

    if (t < D) { sW[t] = w[t] + w[D + t] + w[2 * D + t] + w[3 * D + t]; sS[t] = 0.0f; }
    if (t == 0) sDen = 0.0f;
    const float bsum = bias[0] + bias[1] + bias[2] + bias[3];
    __syncthreads();

    // ---- stage x[blk] into two bf16 LDS tiles (scaled / plain) + column partials ----
    const float* xb   = x + (size_t)blk * (F * D);
    const int col     = (4 * t) & 127;       // constant across k for this thread
    const int chunk   = col >> 3;
    const int ebyte   = (col & 7) << 1;      // 0 or 8
    const float w0 = sW[col], w1 = sW[col + 1], w2 = sW[col + 2], w3 = sW[col + 3];
    float c0 = 0.f, c1 = 0.f, c2 = 0.f, c3 = 0.f;

    char* sAc = reinterpret_cast<char*>(sA);
    char* sBc = reinterpret_cast<char*>(sB);

    #pragma unroll
    for (int k = 0; k < 8; ++k) {
        const int f   = k * 1024 + 4 * t;
        const int row = f >> 7;
        const float4 v = *reinterpret_cast<const float4*>(xb + f);
        c0 += v.x; c1 += v.y; c2 += v.z; c3 += v.w;
        const int a = tile_addr(chunk, row) + ebyte;
        uint2 pb; pb.x = pack2(v.x, v.y);           pb.y = pack2(v.z, v.w);
        uint2 pa; pa.x = pack2(v.x * w0, v.y * w1); pa.y = pack2(v.z * w2, v.w * w3);
        *reinterpret_cast<uint2*>(sBc + a) = pb;
        *reinterpret_cast<uint2*>(sAc + a) = pa;
    }
    atomicAdd(&sS[col],     c0);
    atomicAdd(&sS[col + 1], c1);
    atomicAdd(&sS[col + 2], c2);
    atomicAdd(&sS[col + 3], c3);
    __syncthreads();

    // ---- denominator: fp32 closed form ----
    if (t < D) {
        const float S = sS[t];
        float p = S * S * sW[t];
        #pragma unroll
        for (int off = 32; off; off >>= 1) p += __shfl_xor(p, off, 64);
        if (lane == 0) atomicAdd(&sDen, p);
    }

    // ---- MFMA: wave wv computes output rows [wv*16, wv*16+16) x all 64 cols ----
    f32x4 acc[4] = {{0,0,0,0},{0,0,0,0},{0,0,0,0},{0,0,0,0}};
    const int fr   = lane & 15;       // fragment row/col within 16
    const int kgrp = lane >> 4;       // 0..3 -> k-subchunk
    const int r_a  = wv * 16 + fr;

    #pragma unroll
    for (int s = 0; s < 4; ++s) {     // K = 32 per step
        const int ch = 4 * s + kgrp;
        const bf16x8 afrag = *reinterpret_cast<const bf16x8*>(sAc + tile_addr(ch, r_a));
        #pragma unroll
        for (int tj = 0; tj < 4; ++tj) {
            const bf16x8 bfrag = *reinterpret_cast<const bf16x8*>(sBc + tile_addr(ch, tj * 16 + fr));
            acc[tj] = __builtin_amdgcn_mfma_f32_16x16x32_bf16(afrag, bfrag, acc[tj], 0, 0, 0);
        }
    }
    __syncthreads();   // sDen complete (and tiles no longer needed)

    // ---- epilogue ----
    const float rden  = 1.0f / (sDen + 4096.0f * bsum);
    const int   rbase = wv * 16 + 4 * (lane >> 4);
    float* ob = out + (size_t)blk * (F * F);
    #pragma unroll
    for (int tj = 0; tj < 4; ++tj) {
        const int c = tj * 16 + fr;
        #pragma unroll
        for (int r = 0; r < 4; ++r)
            ob[(size_t)(rbase + r) * F + c] = (acc[tj][r] + bsum) * rden;
    }
}

extern "C" void kernel_launch(void* const* d_in, const int* in_sizes, int n_in,
                              void* d_out, int out_size, void* d_ws, size_t ws_size,
                              hipStream_t stream) {
    const float* x  = (const float*)d_in[0];   // [4096, 64, 128]
    const float* w  = (const float*)d_in[1];   // [4, 128]
    const float* b  = (const float*)d_in[2];   // [4]
    float* out      = (float*)d_out;           // [4096, 64, 64]

    afm_kernel<<<4096, 256, 0, stream>>>(x, w, b, out);
}

// Round 3
// 37.159 us; speedup vs baseline: 2.2010x; 1.2217x over previous
//
#include <hip/hip_runtime.h>
#include <hip/hip_bf16.h>

// AFMAttentionLayer: s[b,i,j] = sum_d x[b,i,d]*x[b,j,d]*wsum[d] + bsum
// out = s / denom[b];  denom[b] = sum_d S_d^2*wsum[d] + F*F*bsum  (fp32 closed form).
// Numerator via bf16 MFMA with a SINGLE LDS tile: B = bf16(X) staged; A-fragments
// derived in-register as bf16(bf16(X)*wsum) (unpack-scale-repack, ~80 VALU/lane).
// LDS ~17.5 KB -> 8 blocks/CU (full wave occupancy). B=4096, F=64, D=128, H=4.

constexpr int F = 64;
constexpr int D = 128;

using bf16x8 = __attribute__((ext_vector_type(8))) short;  // 8 bf16 = 4 VGPRs
using f32x4  = __attribute__((ext_vector_type(4))) float;

// Chunked+swizzled LDS tile: chunk = d>>3 (16), row (64), 8 bf16 = 16 B units.
// byte addr = (((chunk<<6)+row)<<4) ^ ((chunk&7)<<4)
// bank slot16 = (row&7)^(chunk&7): conflict-free for staging writes (row const per
// quarter-wave, chunk varies) and fragment reads (rows vary, chunk varies by kgrp).
__device__ __forceinline__ int tile_addr(int chunk, int row) {
    return ((((chunk << 6) + row) << 4) ^ ((chunk & 7) << 4));
}

// pack two f32 -> one u32 of 2 bf16 (RNE); compiler emits v_cvt_pk_bf16_f32
__device__ __forceinline__ unsigned pk2(float lo, float hi) {
    float2 f2; f2.x = lo; f2.y = hi;
    __hip_bfloat162 h = __float22bfloat162_rn(f2);
    union { __hip_bfloat162 h2; unsigned u; } cv; cv.h2 = h;
    return cv.u;
}
__device__ __forceinline__ float lo16f(unsigned u) { return __uint_as_float(u << 16); }
__device__ __forceinline__ float hi16f(unsigned u) { return __uint_as_float(u & 0xFFFF0000u); }

__global__ __launch_bounds__(256, 8) void afm_kernel(
    const float* __restrict__ x, const float* __restrict__ w,
    const float* __restrict__ bias, float* __restrict__ out)
{
    __shared__ short sB[F * D];   // bf16 X tile, swizzled (16 KB)
    __shared__ float sW[D];
    __shared__ float sS[D];
    __shared__ float sDen;

    const int t    = threadIdx.x;
    const int blk  = blockIdx.x;
    const int lane = t & 63;
    const int wv   = t >> 6;          // wave id 0..3

    if (t < D) { sW[t] = w[t] + w[D + t] + w[2 * D + t] + w[3 * D + t]; sS[t] = 0.0f; }
    if (t == 0) sDen = 0.0f;
    const float bsum = bias[0] + bias[1] + bias[2] + bias[3];
    __syncthreads();

    // ---- stage bf16(x[blk]) into LDS + column partial sums ----
    const float* xb = x + (size_t)blk * (F * D);
    const int col   = (4 * t) & 127;
    const int chunk = col >> 3;
    const int ebyte = (col & 7) << 1;   // 0 or 8
    float c0 = 0.f, c1 = 0.f, c2 = 0.f, c3 = 0.f;
    char* sBc = reinterpret_cast<char*>(sB);

    #pragma unroll
    for (int k = 0; k < 8; ++k) {
        const int f   = k * 1024 + 4 * t;
        const int row = f >> 7;
        const float4 v = *reinterpret_cast<const float4*>(xb + f);
        c0 += v.x; c1 += v.y; c2 += v.z; c3 += v.w;
        uint2 pb; pb.x = pk2(v.x, v.y); pb.y = pk2(v.z, v.w);
        *reinterpret_cast<uint2*>(sBc + tile_addr(chunk, row) + ebyte) = pb;
    }
    // fold lane and lane^32 (same columns), then one atomic per pair
    c0 += __shfl_xor(c0, 32, 64); c1 += __shfl_xor(c1, 32, 64);
    c2 += __shfl_xor(c2, 32, 64); c3 += __shfl_xor(c3, 32, 64);
    if (lane < 32) {
        atomicAdd(&sS[col],     c0);
        atomicAdd(&sS[col + 1], c1);
        atomicAdd(&sS[col + 2], c2);
        atomicAdd(&sS[col + 3], c3);
    }
    __syncthreads();

    // ---- denominator: fp32 closed form ----
    if (t < D) {
        const float S = sS[t];
        float p = S * S * sW[t];
        #pragma unroll
        for (int off = 32; off; off >>= 1) p += __shfl_xor(p, off, 64);
        if (lane == 0) atomicAdd(&sDen, p);
    }

    // ---- MFMA: wave wv computes rows [wv*16, wv*16+16) x all 64 cols ----
    f32x4 acc[4] = {{0,0,0,0},{0,0,0,0},{0,0,0,0},{0,0,0,0}};
    const int fr   = lane & 15;
    const int kgrp = lane >> 4;
    const int r_a  = wv * 16 + fr;

    #pragma unroll
    for (int s = 0; s < 4; ++s) {     // K = 32 per step
        const int ch = 4 * s + kgrp;
        // A fragment: read own bf16 row, unpack -> scale by wsum -> repack
        const uint4  raw = *reinterpret_cast<const uint4*>(sBc + tile_addr(ch, r_a));
        const float4 wa  = *reinterpret_cast<const float4*>(&sW[ch * 8]);
        const float4 wb  = *reinterpret_cast<const float4*>(&sW[ch * 8 + 4]);
        union { uint4 u; bf16x8 v; } af;
        af.u.x = pk2(lo16f(raw.x) * wa.x, hi16f(raw.x) * wa.y);
        af.u.y = pk2(lo16f(raw.y) * wa.z, hi16f(raw.y) * wa.w);
        af.u.z = pk2(lo16f(raw.z) * wb.x, hi16f(raw.z) * wb.y);
        af.u.w = pk2(lo16f(raw.w) * wb.z, hi16f(raw.w) * wb.w);
        #pragma unroll
        for (int tj = 0; tj < 4; ++tj) {
            union { uint4 u; bf16x8 v; } bf;
            bf.u = *reinterpret_cast<const uint4*>(sBc + tile_addr(ch, tj * 16 + fr));
            acc[tj] = __builtin_amdgcn_mfma_f32_16x16x32_bf16(af.v, bf.v, acc[tj], 0, 0, 0);
        }
    }
    __syncthreads();   // sDen complete

    // ---- epilogue ----
    const float rden  = 1.0f / (sDen + 4096.0f * bsum);
    const int   rbase = wv * 16 + 4 * kgrp;
    float* ob = out + (size_t)blk * (F * F);
    #pragma unroll
    for (int tj = 0; tj < 4; ++tj) {
        const int c = tj * 16 + fr;
        #pragma unroll
        for (int r = 0; r < 4; ++r)
            ob[(size_t)(rbase + r) * F + c] = (acc[tj][r] + bsum) * rden;
    }
}

extern "C" void kernel_launch(void* const* d_in, const int* in_sizes, int n_in,
                              void* d_out, int out_size, void* d_ws, size_t ws_size,
                              hipStream_t stream) {
    const float* x  = (const float*)d_in[0];   // [4096, 64, 128]
    const float* w  = (const float*)d_in[1];   // [4, 128]
    const float* b  = (const float*)d_in[2];   // [4]
    float* out      = (float*)d_out;           // [4096, 64, 64]

    afm_kernel<<<4096, 256, 0, stream>>>(x, w, b, out);
}

// Round 4
// 36.021 us; speedup vs baseline: 2.2706x; 1.0316x over previous
//
#include <hip/hip_runtime.h>
#include <hip/hip_bf16.h>

// AFMAttentionLayer: s[b,i,j] = sum_d x[b,i,d]*x[b,j,d]*wsum[d] + bsum
// out = s / denom[b];  denom[b] = sum_d S_d^2*wsum[d] + F*F*bsum (fp32 closed form).
// Numerator via bf16 MFMA, single LDS tile B = bf16(X); A-fragments derived
// in-register (unpack, scale by wsum, repack). Single __syncthreads per block:
// column sums go through per-wave partials sSp (no atomics), denominator is
// computed per-wave redundantly after the barrier. Epilogue exploits symmetry
// of C to store the TRANSPOSE with float4 stores (4 insts/thread instead of 16).
// B=4096, F=64, D=128, H=4.

constexpr int F = 64;
constexpr int D = 128;

using bf16x8 = __attribute__((ext_vector_type(8))) short;  // 8 bf16 = 4 VGPRs
using f32x4  = __attribute__((ext_vector_type(4))) float;

// Chunked+swizzled LDS tile: chunk = d>>3 (16), row (64), 8 bf16 = 16 B units.
// byte addr = (((chunk<<6)+row)<<4) ^ ((chunk&7)<<4); bank slot16 = (row&7)^(chunk&7).
__device__ __forceinline__ int tile_addr(int chunk, int row) {
    return ((((chunk << 6) + row) << 4) ^ ((chunk & 7) << 4));
}

// pack two f32 -> u32 of 2 bf16 (RNE); compiler emits v_cvt_pk_bf16_f32
__device__ __forceinline__ unsigned pk2(float lo, float hi) {
    float2 f2; f2.x = lo; f2.y = hi;
    __hip_bfloat162 h = __float22bfloat162_rn(f2);
    union { __hip_bfloat162 h2; unsigned u; } cv; cv.h2 = h;
    return cv.u;
}
__device__ __forceinline__ float lo16f(unsigned u) { return __uint_as_float(u << 16); }
__device__ __forceinline__ float hi16f(unsigned u) { return __uint_as_float(u & 0xFFFF0000u); }

__global__ __launch_bounds__(256, 8) void afm_kernel(
    const float* __restrict__ x, const float* __restrict__ w,
    const float* __restrict__ bias, float* __restrict__ out)
{
    __shared__ short sB[F * D];        // bf16 X tile, swizzled (16 KB)
    __shared__ float sW[D];            // wsum
    __shared__ float sSp[4][D];        // per-wave column-sum partials (2 KB)

    const int t    = threadIdx.x;
    const int blk  = blockIdx.x;
    const int lane = t & 63;
    const int wv   = t >> 6;

    if (t < D) sW[t] = w[t] + w[D + t] + w[2 * D + t] + w[3 * D + t];
    const float bsum = bias[0] + bias[1] + bias[2] + bias[3];

    // ---- stage bf16(x[blk]) into LDS + per-wave column partial sums ----
    const float* xb = x + (size_t)blk * (F * D);
    const int col   = (4 * t) & 127;        // col quad owned by this thread
    const int chunk = col >> 3;
    const int ebyte = (col & 7) << 1;       // 0 or 8
    float c0 = 0.f, c1 = 0.f, c2 = 0.f, c3 = 0.f;
    char* sBc = reinterpret_cast<char*>(sB);

    #pragma unroll
    for (int k = 0; k < 8; ++k) {
        const int f   = k * 1024 + 4 * t;
        const int row = f >> 7;             // = 8k + (t>>5)
        const float4 v = *reinterpret_cast<const float4*>(xb + f);
        c0 += v.x; c1 += v.y; c2 += v.z; c3 += v.w;
        uint2 pb; pb.x = pk2(v.x, v.y); pb.y = pk2(v.z, v.w);
        *reinterpret_cast<uint2*>(sBc + tile_addr(chunk, row) + ebyte) = pb;
    }
    // fold lane^32 (same col quad, other 8 rows of this wave) -> per-wave partials
    c0 += __shfl_xor(c0, 32, 64); c1 += __shfl_xor(c1, 32, 64);
    c2 += __shfl_xor(c2, 32, 64); c3 += __shfl_xor(c3, 32, 64);
    if (lane < 32) {                        // col == 4*lane here
        float4 cs; cs.x = c0; cs.y = c1; cs.z = c2; cs.w = c3;
        *reinterpret_cast<float4*>(&sSp[wv][col]) = cs;
    }
    __syncthreads();   // the ONLY barrier: tile + sW + sSp all visible

    // ---- per-wave denominator (redundant per wave; overlaps MFMA scheduling) ----
    const float S0 = sSp[0][lane] + sSp[1][lane] + sSp[2][lane] + sSp[3][lane];
    const float S1 = sSp[0][64 + lane] + sSp[1][64 + lane] + sSp[2][64 + lane] + sSp[3][64 + lane];
    float p = S0 * S0 * sW[lane] + S1 * S1 * sW[64 + lane];
    #pragma unroll
    for (int off = 32; off; off >>= 1) p += __shfl_xor(p, off, 64);

    // ---- MFMA: wave wv computes rows [wv*16, wv*16+16) x all 64 cols ----
    f32x4 acc[4] = {{0,0,0,0},{0,0,0,0},{0,0,0,0},{0,0,0,0}};
    const int fr   = lane & 15;
    const int kgrp = lane >> 4;
    const int r_a  = wv * 16 + fr;

    #pragma unroll
    for (int s = 0; s < 4; ++s) {           // K = 32 per step
        const int ch = 4 * s + kgrp;
        // A fragment: read own bf16 row, unpack -> scale by wsum -> repack
        const uint4  raw = *reinterpret_cast<const uint4*>(sBc + tile_addr(ch, r_a));
        const float4 wa  = *reinterpret_cast<const float4*>(&sW[ch * 8]);
        const float4 wb  = *reinterpret_cast<const float4*>(&sW[ch * 8 + 4]);
        union { uint4 u; bf16x8 v; } af;
        af.u.x = pk2(lo16f(raw.x) * wa.x, hi16f(raw.x) * wa.y);
        af.u.y = pk2(lo16f(raw.y) * wa.z, hi16f(raw.y) * wa.w);
        af.u.z = pk2(lo16f(raw.z) * wb.x, hi16f(raw.z) * wb.y);
        af.u.w = pk2(lo16f(raw.w) * wb.z, hi16f(raw.w) * wb.w);
        #pragma unroll
        for (int tj = 0; tj < 4; ++tj) {
            union { uint4 u; bf16x8 v; } bf;
            bf.u = *reinterpret_cast<const uint4*>(sBc + tile_addr(ch, tj * 16 + fr));
            acc[tj] = __builtin_amdgcn_mfma_f32_16x16x32_bf16(af.v, bf.v, acc[tj], 0, 0, 0);
        }
    }

    // ---- epilogue: C symmetric -> store transpose with float4 stores ----
    const float rden  = 1.0f / (p + 4096.0f * bsum);
    const int   rbase = wv * 16 + 4 * kgrp;      // contiguous in transposed layout
    float* ob = out + (size_t)blk * (F * F);
    #pragma unroll
    for (int tj = 0; tj < 4; ++tj) {
        float4 o;
        o.x = (acc[tj][0] + bsum) * rden;
        o.y = (acc[tj][1] + bsum) * rden;
        o.z = (acc[tj][2] + bsum) * rden;
        o.w = (acc[tj][3] + bsum) * rden;
        *reinterpret_cast<float4*>(ob + (size_t)(tj * 16 + fr) * F + rbase) = o;
    }
}

extern "C" void kernel_launch(void* const* d_in, const int* in_sizes, int n_in,
                              void* d_out, int out_size, void* d_ws, size_t ws_size,
                              hipStream_t stream) {
    const float* x  = (const float*)d_in[0];   // [4096, 64, 128]
    const float* w  = (const float*)d_in[1];   // [4, 128]
    const float* b  = (const float*)d_in[2];   // [4]
    float* out      = (float*)d_out;           // [4096, 64, 64]

    afm_kernel<<<4096, 256, 0, stream>>>(x, w, b, out);
}